// Round 2
// baseline (264.606 us; speedup 1.0000x reference)
//
#include <hip/hip_runtime.h>

typedef float floatx4 __attribute__((ext_vector_type(4)));
typedef short s16x8 __attribute__((ext_vector_type(8)));  // 8 bf16 (4 VGPRs)

#define WG 256
#define NBUCK 512   // buckets of 256 nodes -> covers N <= 131072 (here N=100000)
#define BSH 8       // 256 nodes per bucket
#define EBLK 512    // blocks for the edge-build half of k_main (2 blocks/CU)
#define CAP 8192    // per-bucket capacity; uniform-random mean 4092, sigma 64

__device__ inline unsigned pack_bf16_rne(float a, float b) {
    unsigned ua = __float_as_uint(a), ub = __float_as_uint(b);
    ua = (ua + 0x7FFFu + ((ua >> 16) & 1u)) >> 16;
    ub = (ub + 0x7FFFu + ((ub >> 16) & 1u)) >> 16;
    return ua | (ub << 16);
}

union FragU {
    unsigned u[4];
    uint4 q;
    s16x8 v;
};

// ---------------------------------------------------------------------------
// One-time: pack W (256x64 f32) into MFMA B-fragment bf16 layout (2048 uint4,
// 32 KB). The GEMM blocks read fragments straight from this buffer (L2-hot,
// coalesced 1 KB/wave loads) - no LDS staging. Also zeroes the bucket cursors.
__global__ __launch_bounds__(WG) void k_packw(const float* __restrict__ W,
                                              uint4* __restrict__ wpack,
                                              int* __restrict__ cursor) {
    const int q = blockIdx.x * WG + threadIdx.x;  // [0, 2048)
    if (q < NBUCK) cursor[q] = 0;
    const int kb = q >> 8, nt = (q >> 6) & 3, ln = q & 63;
    const int quad = ln >> 4, l15 = ln & 15;
    const int col = nt * 16 + l15;
    const int krow = kb * 32 + quad * 8;
    unsigned up[4];
#pragma unroll
    for (int p = 0; p < 4; p++) {
        float a = W[(krow + 2 * p) * 64 + col];
        float b2 = W[(krow + 2 * p + 1) * 64 + col];
        up[p] = pack_bf16_rne(a, b2);
    }
    uint4 pk = {up[0], up[1], up[2], up[3]};
    wpack[q] = pk;
}

// ---------------------------------------------------------------------------
// Fused: blocks [0, EBLK) bucket the edges, blocks [EBLK, EBLK+gemmB) run the
// MFMA gemm writing UNscaled h = x@W as bf16. Shared memory is only the 4.1 KB
// the edge branch needs, so occupancy is wave-limited (~8 blocks/CU) instead
// of LDS-limited (5 blocks/CU at the old 32 KB) - the whole kernel was
// latency-bound at 32% occupancy / 17% HBM.
__global__ __launch_bounds__(WG) void k_main(const void* __restrict__ ei, int* __restrict__ cursor,
                                             unsigned* __restrict__ ebuf, int E,
                                             const float* __restrict__ x, const uint4* __restrict__ wpack,
                                             unsigned short* __restrict__ g, int N) {
    __shared__ int hh[NBUCK];
    __shared__ int hbase[NBUCK];
    __shared__ int s32flag;
    const int t = threadIdx.x;

    if ((int)blockIdx.x < EBLK) {
        // ---------------- edge-bucket branch ----------------
        if (t == 0) s32flag = 0;
        for (int i = t; i < NBUCK; i += WG) hh[i] = 0;
        __syncthreads();
        {
            const int* w = (const int*)ei;
            int nz = 0;
            for (int j = t; j < 4096; j += WG) nz |= (w[2 * j + 1] != 0);
            if (nz) atomicOr(&s32flag, 1);
        }
        __syncthreads();
        const bool i32 = (s32flag != 0);
        const int chunk = (E + EBLK - 1) / EBLK;
        const int s = blockIdx.x * chunk;
        const int eend = min(E, s + chunk);
        if (i32) {
            const int* pd = (const int*)ei + E;
            for (int e = s + t; e < eend; e += WG) atomicAdd(&hh[pd[e] >> BSH], 1);
        } else {
            const long long* pd = (const long long*)ei + E;
            for (int e = s + t; e < eend; e += WG) atomicAdd(&hh[(int)pd[e] >> BSH], 1);
        }
        __syncthreads();
        for (int i = t; i < NBUCK; i += WG) {
            int c = hh[i];
            hbase[i] = c ? atomicAdd(&cursor[i], c) : 0;
            hh[i] = 0;  // reuse as local cursor
        }
        __syncthreads();
        for (int e = s + t; e < eend; e += WG) {
            int sN, dN;
            if (i32) {
                const int* p = (const int*)ei;
                sN = p[e];
                dN = p[E + e];
            } else {
                const long long* p = (const long long*)ei;
                sN = (int)p[e];
                dN = (int)p[(long long)E + e];
            }
            int bkt = dN >> BSH;
            int pos = hbase[bkt] + atomicAdd(&hh[bkt], 1);
            if (pos < CAP) ebuf[(size_t)bkt * CAP + pos] = (unsigned)sN | ((unsigned)(dN & 255) << 24);
        }
    } else {
        // ---------------- GEMM branch (MFMA 16x16x32 bf16) ----------------
        // Layouts: A[m=lane&15][k=quad*8+j], B[n=lane&15][k=...],
        // D[m=quad*4+r][n=lane&15]. B fragments read directly from the
        // pre-packed global buffer (L2-hot, coalesced); x streamed with a
        // depth-1 prefetch so VGPR stays ~60 -> ~8 waves/SIMD.
        const int bb = blockIdx.x - EBLK;
        const int wv = t >> 6;
        const int lane = t & 63;
        const int quad = lane >> 4, l15 = lane & 15;

        long long arow = (long long)bb * 64 + wv * 16 + l15;
        if (arow >= N) arow = N - 1;  // clamp loads; stores guarded below
        const float* xr = x + arow * 256 + quad * 8;
        const uint4* wp = wpack + lane;

        floatx4 acc[4];
#pragma unroll
        for (int nt = 0; nt < 4; nt++) acc[nt] = 0.f;

        floatx4 xc0 = *(const floatx4*)(xr);
        floatx4 xc1 = *(const floatx4*)(xr + 4);

#pragma unroll
        for (int kb = 0; kb < 8; kb++) {
            floatx4 xn0, xn1;
            if (kb < 7) {  // prefetch next k-block of x (HBM) under this one's work
                xn0 = *(const floatx4*)(xr + (kb + 1) * 32);
                xn1 = *(const floatx4*)(xr + (kb + 1) * 32 + 4);
            }
            FragU b0, b1, b2, b3;  // coalesced 1 KB/wave reads, L2-hot
            b0.q = wp[(kb * 4 + 0) * 64];
            b1.q = wp[(kb * 4 + 1) * 64];
            b2.q = wp[(kb * 4 + 2) * 64];
            b3.q = wp[(kb * 4 + 3) * 64];
            FragU a;
            a.u[0] = pack_bf16_rne(xc0[0], xc0[1]);
            a.u[1] = pack_bf16_rne(xc0[2], xc0[3]);
            a.u[2] = pack_bf16_rne(xc1[0], xc1[1]);
            a.u[3] = pack_bf16_rne(xc1[2], xc1[3]);
            acc[0] = __builtin_amdgcn_mfma_f32_16x16x32_bf16(a.v, b0.v, acc[0], 0, 0, 0);
            acc[1] = __builtin_amdgcn_mfma_f32_16x16x32_bf16(a.v, b1.v, acc[1], 0, 0, 0);
            acc[2] = __builtin_amdgcn_mfma_f32_16x16x32_bf16(a.v, b2.v, acc[2], 0, 0, 0);
            acc[3] = __builtin_amdgcn_mfma_f32_16x16x32_bf16(a.v, b3.v, acc[3], 0, 0, 0);
            if (kb < 7) {
                xc0 = xn0;
                xc1 = xn1;
            }
        }

        const long long orow0 = (long long)bb * 64 + wv * 16 + quad * 4;
#pragma unroll
        for (int r = 0; r < 4; r++) {
            const long long orow = orow0 + r;
            if (orow < N) {
#pragma unroll
                for (int nt = 0; nt < 4; nt++) {
                    float v = acc[nt][r];  // UNscaled h
                    unsigned uv = __float_as_uint(v);
                    uv = (uv + 0x7FFFu + ((uv >> 16) & 1u)) >> 16;
                    g[orow * 64 + nt * 16 + l15] = (unsigned short)uv;
                }
            }
        }
    }
}

// ---------------------------------------------------------------------------
// CSR finish: per-bucket exclusive base, per-node degree (+self-loop), dinv,
// and the scatter of bucketed edges into final CSR order. Short (391 blocks);
// depends on the edge-bucket half of k_main, hence its own dispatch.
__global__ __launch_bounds__(WG) void k_csr(const unsigned* __restrict__ ebuf, const int* __restrict__ cursor,
                                            int* __restrict__ off, int* __restrict__ srcs,
                                            float* __restrict__ dinv, int N, int nbuse) {
    __shared__ int red[256];
    __shared__ int h[256];
    __shared__ int sc[256];
    __shared__ int cur[256];
    const int t = threadIdx.x;
    const int b = blockIdx.x;
    const int node0 = b << BSH;
    const int rows = min(256, N - node0);
    int part = 0;
    for (int i = t; i < b; i += WG) part += min(cursor[i], CAP);
    red[t] = part;
    h[t] = 0;
    __syncthreads();
    for (int d = WG / 2; d > 0; d >>= 1) {
        if (t < d) red[t] += red[t + d];
        __syncthreads();
    }
    const int ebase = red[0];
    const int cnt = min(cursor[b], CAP);
    const unsigned* eb = ebuf + (size_t)b * CAP;
    for (int j = t; j < cnt; j += WG) atomicAdd(&h[eb[j] >> 24], 1);
    __syncthreads();
    const int deg = (t < rows) ? h[t] + 1 : 0;  // +1 self-loop
    sc[t] = deg;
    __syncthreads();
    for (int d = 1; d < 256; d <<= 1) {
        int a = (t >= d) ? sc[t - d] : 0;
        __syncthreads();
        sc[t] += a;
        __syncthreads();
    }
    const int basef = ebase + node0;  // prior edges + prior self-loops
    const int local = sc[t] - deg;
    if (t < rows) {
        off[node0 + t] = basef + local;
        srcs[basef + local] = node0 + t;  // self-loop at slot 0
        cur[t] = local + 1;
        dinv[node0 + t] = rsqrtf((float)deg);
    }
    if (b == nbuse - 1 && t == 0) off[N] = ebase + cnt + N;
    __syncthreads();
    for (int j = t; j < cnt; j += WG) {
        unsigned w = eb[j];
        int dl = (int)(w >> 24);
        int pos = basef + atomicAdd(&cur[dl], 1);
        srcs[pos] = (int)(w & 0xFFFFFFu);
    }
}

// One wave per dst node, eight 8-lane groups, 16 B/lane row reads. srcs is
// software-pipelined one step ahead so the s -> (dinv[s], g-row) dependent
// chain spans iterations. Accumulates a += dinv[s]*row (h is unscaled);
// epilogue applies dinv[d] and bias. Zero atomics.
__global__ __launch_bounds__(WG) void k_gather(const unsigned short* __restrict__ g,
                                               const int* __restrict__ off, const int* __restrict__ srcs,
                                               const float* __restrict__ dinv, const float* __restrict__ bias,
                                               float* __restrict__ out, int N) {
    int wid = (blockIdx.x * WG + threadIdx.x) >> 6;
    int lane = threadIdx.x & 63;
    if (wid >= N) return;
    int grp = lane >> 3;
    int c8 = (lane & 7) * 8;  // cols c8 .. c8+7
    int e0 = off[wid], e1 = off[wid + 1];
    float a0 = 0.f, a1 = 0.f, a2 = 0.f, a3 = 0.f, a4 = 0.f, a5 = 0.f, a6 = 0.f, a7 = 0.f;
    int e = e0 + grp;
    int s = (e < e1) ? srcs[e] : 0;
    while (e < e1) {
        int en = e + 8;
        int sn = (en < e1) ? srcs[en] : 0;  // prefetch next iteration's src
        float ds = dinv[s];
        uint4 v = *(const uint4*)(g + (long long)s * 64 + c8);
        a0 += ds * __uint_as_float(v.x << 16);
        a1 += ds * __uint_as_float(v.x & 0xFFFF0000u);
        a2 += ds * __uint_as_float(v.y << 16);
        a3 += ds * __uint_as_float(v.y & 0xFFFF0000u);
        a4 += ds * __uint_as_float(v.z << 16);
        a5 += ds * __uint_as_float(v.z & 0xFFFF0000u);
        a6 += ds * __uint_as_float(v.w << 16);
        a7 += ds * __uint_as_float(v.w & 0xFFFF0000u);
        s = sn;
        e = en;
    }
#pragma unroll
    for (int m = 8; m <= 32; m <<= 1) {
        a0 += __shfl_xor(a0, m, 64);
        a1 += __shfl_xor(a1, m, 64);
        a2 += __shfl_xor(a2, m, 64);
        a3 += __shfl_xor(a3, m, 64);
        a4 += __shfl_xor(a4, m, 64);
        a5 += __shfl_xor(a5, m, 64);
        a6 += __shfl_xor(a6, m, 64);
        a7 += __shfl_xor(a7, m, 64);
    }
    if (grp == 0) {
        float d = dinv[wid];
        const floatx4 b0 = *(const floatx4*)(bias + c8);
        const floatx4 b1 = *(const floatx4*)(bias + c8 + 4);
        floatx4 o0, o1;
        o0[0] = d * a0 + b0[0];
        o0[1] = d * a1 + b0[1];
        o0[2] = d * a2 + b0[2];
        o0[3] = d * a3 + b0[3];
        o1[0] = d * a4 + b1[0];
        o1[1] = d * a5 + b1[1];
        o1[2] = d * a6 + b1[2];
        o1[3] = d * a7 + b1[3];
        *(floatx4*)(out + (long long)wid * 64 + c8) = o0;
        *(floatx4*)(out + (long long)wid * 64 + c8 + 4) = o1;
    }
}

extern "C" void kernel_launch(void* const* d_in, const int* in_sizes, int n_in,
                              void* d_out, int out_size, void* d_ws, size_t ws_size,
                              hipStream_t stream) {
    const float* x = (const float*)d_in[0];
    const void* ei = d_in[1];
    const float* W = (const float*)d_in[2];
    const float* b = (const float*)d_in[3];
    float* out = (float*)d_out;

    const int N = in_sizes[0] / 256;  // requires N < 2^24 and N <= 131072 (here 100000)
    const int E = in_sizes[1] / 2;
    const int NBUSE = (N + 255) >> BSH;       // 391 buckets used
    const int GEMMB = (N + 63) / 64;          // 1563 gemm blocks

    char* ws = (char*)d_ws;
    size_t o = 0;
    auto alloc = [&](size_t bytes) -> void* {
        void* p = ws + o;
        o += (bytes + 255) & ~(size_t)255;
        return p;
    };
    float* dinv = (float*)alloc((size_t)N * 4);
    unsigned short* g = (unsigned short*)alloc((size_t)N * 64 * 2);   // bf16 h, 12.8 MB
    unsigned* ebuf = (unsigned*)alloc((size_t)NBUSE * CAP * 4);       // bucketed edges, 12.8 MB
    int* cursor = (int*)alloc((size_t)NBUCK * 4);
    int* off = (int*)alloc((size_t)(N + 1) * 4);                      // final CSR offsets
    int* srcs = (int*)alloc((size_t)(E + N) * 4);                     // final CSR srcs (+self-loops)
    uint4* wpack = (uint4*)alloc((size_t)2048 * 16);                  // frag-layout bf16 W, 32 KB
    if (o > ws_size) return;  // fail visibly rather than corrupt

    k_packw<<<8, WG, 0, stream>>>(W, wpack, cursor);
    k_main<<<EBLK + GEMMB, WG, 0, stream>>>(ei, cursor, ebuf, E, x, wpack, g, N);
    k_csr<<<NBUSE, WG, 0, stream>>>(ebuf, cursor, off, srcs, dinv, N, NBUSE);
    k_gather<<<(N * 64 + WG - 1) / WG, WG, 0, stream>>>(g, off, srcs, dinv, b, out, N);
}

// Round 3
// 252.422 us; speedup vs baseline: 1.0483x; 1.0483x over previous
//
#include <hip/hip_runtime.h>

typedef float floatx4 __attribute__((ext_vector_type(4)));
typedef short s16x8 __attribute__((ext_vector_type(8)));  // 8 bf16 (4 VGPRs)

#define WG 256
#define NBUCK 512   // buckets of 256 nodes -> covers N <= 131072 (here N=100000)
#define BSH 8       // 256 nodes per bucket
#define EBLK 512    // blocks for the edge-build half of k_main (2 blocks/CU)
#define CAP 8192    // per-bucket capacity; uniform-random mean 4092, sigma 64
#define MAXIT 16    // per-thread cached edges; covers chunk <= 4096 (E <= 2M)

__device__ inline unsigned pack_bf16_rne(float a, float b) {
    unsigned ua = __float_as_uint(a), ub = __float_as_uint(b);
    ua = (ua + 0x7FFFu + ((ua >> 16) & 1u)) >> 16;
    ub = (ub + 0x7FFFu + ((ub >> 16) & 1u)) >> 16;
    return ua | (ub << 16);
}

union FragU {
    unsigned u[4];
    uint4 q;
    s16x8 v;
};

// ---------------------------------------------------------------------------
// One-time: pack W (256x64 f32) into MFMA B-fragment bf16 layout (2048 uint4,
// 32 KB). GEMM blocks read fragments straight from this buffer (L2-hot,
// coalesced 1 KB/wave loads). Also zeroes the bucket cursors.
__global__ __launch_bounds__(WG) void k_packw(const float* __restrict__ W,
                                              uint4* __restrict__ wpack,
                                              int* __restrict__ cursor) {
    const int q = blockIdx.x * WG + threadIdx.x;  // [0, 2048)
    if (q < NBUCK) cursor[q] = 0;
    const int kb = q >> 8, nt = (q >> 6) & 3, ln = q & 63;
    const int quad = ln >> 4, l15 = ln & 15;
    const int col = nt * 16 + l15;
    const int krow = kb * 32 + quad * 8;
    unsigned up[4];
#pragma unroll
    for (int p = 0; p < 4; p++) {
        float a = W[(krow + 2 * p) * 64 + col];
        float b2 = W[(krow + 2 * p + 1) * 64 + col];
        up[p] = pack_bf16_rne(a, b2);
    }
    uint4 pk = {up[0], up[1], up[2], up[3]};
    wpack[q] = pk;
}

// ---------------------------------------------------------------------------
// Fused: blocks [0, EBLK) bucket the edges, blocks [EBLK, EBLK+gemmB) run the
// MFMA gemm writing UNscaled h = x@W as bf16.
// GEMM design point: ALL 16 x-row loads in flight (64 VGPR, pinned live via
// inline-asm keep-alive - sched_barrier alone failed: VGPR_Count was 48/56,
// proving the loads were being re-sunk into the K loop), B fragments depth-1
// prefetched from L2-hot wpack, zero LDS / zero barriers in this branch.
// __launch_bounds__(WG,4) pins the 128-VGPR / 4-waves-per-SIMD design point.
__global__ __launch_bounds__(WG, 4) void k_main(const void* __restrict__ ei, int* __restrict__ cursor,
                                                unsigned* __restrict__ ebuf, int E,
                                                const float* __restrict__ x, const uint4* __restrict__ wpack,
                                                unsigned short* __restrict__ g, int N) {
    __shared__ int hh[NBUCK];
    __shared__ int hbase[NBUCK];
    __shared__ int s32flag;
    const int t = threadIdx.x;

    if ((int)blockIdx.x < EBLK) {
        // ---------------- edge-bucket branch ----------------
        if (t == 0) s32flag = 0;
        for (int i = t; i < NBUCK; i += WG) hh[i] = 0;
        __syncthreads();
        {
            const int* w = (const int*)ei;
            int nz = 0;
            for (int j = t; j < 4096; j += WG) nz |= (w[2 * j + 1] != 0);
            if (nz) atomicOr(&s32flag, 1);
        }
        __syncthreads();
        const bool i32 = (s32flag != 0);
        const int chunk = (E + EBLK - 1) / EBLK;
        const int s = blockIdx.x * chunk;
        const int eend = min(E, s + chunk);

        if (chunk <= MAXIT * WG) {
            // Register-cached two-pass: edges read from HBM once; pass 2's
            // per-edge chain is LDS-atomic -> store (no reload in the chain).
            unsigned ew[MAXIT];
            unsigned short ebk[MAXIT];
#pragma unroll
            for (int i = 0; i < MAXIT; i++) {
                const int e = s + t + i * WG;
                ebk[i] = 0xFFFFu;
                if (e < eend) {
                    int sN, dN;
                    if (i32) {
                        const int* p = (const int*)ei;
                        sN = p[e];
                        dN = p[E + e];
                    } else {
                        const long long* p = (const long long*)ei;
                        sN = (int)p[e];
                        dN = (int)p[(long long)E + e];
                    }
                    ew[i] = (unsigned)sN | ((unsigned)(dN & 255) << 24);
                    ebk[i] = (unsigned short)(dN >> BSH);
                    atomicAdd(&hh[dN >> BSH], 1);
                }
            }
            __syncthreads();
            for (int i = t; i < NBUCK; i += WG) {
                int c = hh[i];
                hbase[i] = c ? atomicAdd(&cursor[i], c) : 0;
                hh[i] = 0;  // reuse as local cursor
            }
            __syncthreads();
#pragma unroll
            for (int i = 0; i < MAXIT; i++) {
                if (ebk[i] != 0xFFFFu) {
                    const int bkt = ebk[i];
                    const int pos = hbase[bkt] + atomicAdd(&hh[bkt], 1);
                    if (pos < CAP) ebuf[(size_t)bkt * CAP + pos] = ew[i];
                }
            }
        } else {
            // Fallback (E too large for the register cache): original 2-pass.
            if (i32) {
                const int* pd = (const int*)ei + E;
                for (int e = s + t; e < eend; e += WG) atomicAdd(&hh[pd[e] >> BSH], 1);
            } else {
                const long long* pd = (const long long*)ei + E;
                for (int e = s + t; e < eend; e += WG) atomicAdd(&hh[(int)pd[e] >> BSH], 1);
            }
            __syncthreads();
            for (int i = t; i < NBUCK; i += WG) {
                int c = hh[i];
                hbase[i] = c ? atomicAdd(&cursor[i], c) : 0;
                hh[i] = 0;
            }
            __syncthreads();
            for (int e = s + t; e < eend; e += WG) {
                int sN, dN;
                if (i32) {
                    const int* p = (const int*)ei;
                    sN = p[e];
                    dN = p[E + e];
                } else {
                    const long long* p = (const long long*)ei;
                    sN = (int)p[e];
                    dN = (int)p[(long long)E + e];
                }
                int bkt = dN >> BSH;
                int pos = hbase[bkt] + atomicAdd(&hh[bkt], 1);
                if (pos < CAP) ebuf[(size_t)bkt * CAP + pos] = (unsigned)sN | ((unsigned)(dN & 255) << 24);
            }
        }
    } else {
        // ---------------- GEMM branch (MFMA 16x16x32 bf16) ----------------
        // Layouts: A[m=lane&15][k=quad*8+j], B[n=lane&15][k=...],
        // D[m=quad*4+r][n=lane&15].
        const int bb = blockIdx.x - EBLK;
        const int wv = t >> 6;
        const int lane = t & 63;
        const int quad = lane >> 4, l15 = lane & 15;

        long long arow = (long long)bb * 64 + wv * 16 + l15;
        if (arow >= N) arow = N - 1;  // clamp loads; stores guarded below
        const float* xr = x + arow * 256 + quad * 8;
        const uint4* wp = wpack + lane;

        // Issue all 16 x-row loads (one HBM round trip for the whole tile).
        floatx4 xv[8][2];
#pragma unroll
        for (int kb = 0; kb < 8; kb++) {
            xv[kb][0] = *(const floatx4*)(xr + kb * 32);
            xv[kb][1] = *(const floatx4*)(xr + kb * 32 + 4);
        }
        // Pin all 16 results live so the compiler cannot re-sink the loads
        // into the K loop (rule #17 liveness trick; sched_barrier alone
        // demonstrably failed - VGPR_Count 48/56 in prior rounds).
#pragma unroll
        for (int kb = 0; kb < 8; kb++) {
            asm volatile("" : "+v"(xv[kb][0]), "+v"(xv[kb][1]));
        }
        __builtin_amdgcn_sched_barrier(0);

        floatx4 acc[4];
#pragma unroll
        for (int nt = 0; nt < 4; nt++) acc[nt] = 0.f;

        // B depth-1 prefetch from L2-hot wpack (coalesced 1 KB/wave reads).
        FragU bc0, bc1, bc2, bc3;
        bc0.q = wp[0 * 64];
        bc1.q = wp[1 * 64];
        bc2.q = wp[2 * 64];
        bc3.q = wp[3 * 64];

#pragma unroll
        for (int kb = 0; kb < 8; kb++) {
            FragU bn0, bn1, bn2, bn3;
            if (kb < 7) {
                bn0.q = wp[((kb + 1) * 4 + 0) * 64];
                bn1.q = wp[((kb + 1) * 4 + 1) * 64];
                bn2.q = wp[((kb + 1) * 4 + 2) * 64];
                bn3.q = wp[((kb + 1) * 4 + 3) * 64];
            }
            FragU a;
            a.u[0] = pack_bf16_rne(xv[kb][0][0], xv[kb][0][1]);
            a.u[1] = pack_bf16_rne(xv[kb][0][2], xv[kb][0][3]);
            a.u[2] = pack_bf16_rne(xv[kb][1][0], xv[kb][1][1]);
            a.u[3] = pack_bf16_rne(xv[kb][1][2], xv[kb][1][3]);
            acc[0] = __builtin_amdgcn_mfma_f32_16x16x32_bf16(a.v, bc0.v, acc[0], 0, 0, 0);
            acc[1] = __builtin_amdgcn_mfma_f32_16x16x32_bf16(a.v, bc1.v, acc[1], 0, 0, 0);
            acc[2] = __builtin_amdgcn_mfma_f32_16x16x32_bf16(a.v, bc2.v, acc[2], 0, 0, 0);
            acc[3] = __builtin_amdgcn_mfma_f32_16x16x32_bf16(a.v, bc3.v, acc[3], 0, 0, 0);
            if (kb < 7) {
                bc0 = bn0;
                bc1 = bn1;
                bc2 = bn2;
                bc3 = bn3;
            }
        }

        const long long orow0 = (long long)bb * 64 + wv * 16 + quad * 4;
#pragma unroll
        for (int r = 0; r < 4; r++) {
            const long long orow = orow0 + r;
            if (orow < N) {
#pragma unroll
                for (int nt = 0; nt < 4; nt++) {
                    float v = acc[nt][r];  // UNscaled h
                    unsigned uv = __float_as_uint(v);
                    uv = (uv + 0x7FFFu + ((uv >> 16) & 1u)) >> 16;
                    g[orow * 64 + nt * 16 + l15] = (unsigned short)uv;
                }
            }
        }
    }
}

// ---------------------------------------------------------------------------
// CSR finish: per-bucket exclusive base, per-node degree (+self-loop), dinv,
// and the scatter of bucketed edges into final CSR order. Short (391 blocks);
// depends on the edge-bucket half of k_main, hence its own dispatch.
__global__ __launch_bounds__(WG) void k_csr(const unsigned* __restrict__ ebuf, const int* __restrict__ cursor,
                                            int* __restrict__ off, int* __restrict__ srcs,
                                            float* __restrict__ dinv, int N, int nbuse) {
    __shared__ int red[256];
    __shared__ int h[256];
    __shared__ int sc[256];
    __shared__ int cur[256];
    const int t = threadIdx.x;
    const int b = blockIdx.x;
    const int node0 = b << BSH;
    const int rows = min(256, N - node0);
    int part = 0;
    for (int i = t; i < b; i += WG) part += min(cursor[i], CAP);
    red[t] = part;
    h[t] = 0;
    __syncthreads();
    for (int d = WG / 2; d > 0; d >>= 1) {
        if (t < d) red[t] += red[t + d];
        __syncthreads();
    }
    const int ebase = red[0];
    const int cnt = min(cursor[b], CAP);
    const unsigned* eb = ebuf + (size_t)b * CAP;
    for (int j = t; j < cnt; j += WG) atomicAdd(&h[eb[j] >> 24], 1);
    __syncthreads();
    const int deg = (t < rows) ? h[t] + 1 : 0;  // +1 self-loop
    sc[t] = deg;
    __syncthreads();
    for (int d = 1; d < 256; d <<= 1) {
        int a = (t >= d) ? sc[t - d] : 0;
        __syncthreads();
        sc[t] += a;
        __syncthreads();
    }
    const int basef = ebase + node0;  // prior edges + prior self-loops
    const int local = sc[t] - deg;
    if (t < rows) {
        off[node0 + t] = basef + local;
        srcs[basef + local] = node0 + t;  // self-loop at slot 0
        cur[t] = local + 1;
        dinv[node0 + t] = rsqrtf((float)deg);
    }
    if (b == nbuse - 1 && t == 0) off[N] = ebase + cnt + N;
    __syncthreads();
    for (int j = t; j < cnt; j += WG) {
        unsigned w = eb[j];
        int dl = (int)(w >> 24);
        int pos = basef + atomicAdd(&cur[dl], 1);
        srcs[pos] = (int)(w & 0xFFFFFFu);
    }
}

// One wave per dst node, eight 8-lane groups, 16 B/lane row reads. srcs is
// software-pipelined one step ahead so the s -> (dinv[s], g-row) dependent
// chain spans iterations. Accumulates a += dinv[s]*row (h is unscaled);
// epilogue applies dinv[d] and bias. Zero atomics.
__global__ __launch_bounds__(WG) void k_gather(const unsigned short* __restrict__ g,
                                               const int* __restrict__ off, const int* __restrict__ srcs,
                                               const float* __restrict__ dinv, const float* __restrict__ bias,
                                               float* __restrict__ out, int N) {
    int wid = (blockIdx.x * WG + threadIdx.x) >> 6;
    int lane = threadIdx.x & 63;
    if (wid >= N) return;
    int grp = lane >> 3;
    int c8 = (lane & 7) * 8;  // cols c8 .. c8+7
    int e0 = off[wid], e1 = off[wid + 1];
    float a0 = 0.f, a1 = 0.f, a2 = 0.f, a3 = 0.f, a4 = 0.f, a5 = 0.f, a6 = 0.f, a7 = 0.f;
    int e = e0 + grp;
    int s = (e < e1) ? srcs[e] : 0;
    while (e < e1) {
        int en = e + 8;
        int sn = (en < e1) ? srcs[en] : 0;  // prefetch next iteration's src
        float ds = dinv[s];
        uint4 v = *(const uint4*)(g + (long long)s * 64 + c8);
        a0 += ds * __uint_as_float(v.x << 16);
        a1 += ds * __uint_as_float(v.x & 0xFFFF0000u);
        a2 += ds * __uint_as_float(v.y << 16);
        a3 += ds * __uint_as_float(v.y & 0xFFFF0000u);
        a4 += ds * __uint_as_float(v.z << 16);
        a5 += ds * __uint_as_float(v.z & 0xFFFF0000u);
        a6 += ds * __uint_as_float(v.w << 16);
        a7 += ds * __uint_as_float(v.w & 0xFFFF0000u);
        s = sn;
        e = en;
    }
#pragma unroll
    for (int m = 8; m <= 32; m <<= 1) {
        a0 += __shfl_xor(a0, m, 64);
        a1 += __shfl_xor(a1, m, 64);
        a2 += __shfl_xor(a2, m, 64);
        a3 += __shfl_xor(a3, m, 64);
        a4 += __shfl_xor(a4, m, 64);
        a5 += __shfl_xor(a5, m, 64);
        a6 += __shfl_xor(a6, m, 64);
        a7 += __shfl_xor(a7, m, 64);
    }
    if (grp == 0) {
        float d = dinv[wid];
        const floatx4 b0 = *(const floatx4*)(bias + c8);
        const floatx4 b1 = *(const floatx4*)(bias + c8 + 4);
        floatx4 o0, o1;
        o0[0] = d * a0 + b0[0];
        o0[1] = d * a1 + b0[1];
        o0[2] = d * a2 + b0[2];
        o0[3] = d * a3 + b0[3];
        o1[0] = d * a4 + b1[0];
        o1[1] = d * a5 + b1[1];
        o1[2] = d * a6 + b1[2];
        o1[3] = d * a7 + b1[3];
        *(floatx4*)(out + (long long)wid * 64 + c8) = o0;
        *(floatx4*)(out + (long long)wid * 64 + c8 + 4) = o1;
    }
}

extern "C" void kernel_launch(void* const* d_in, const int* in_sizes, int n_in,
                              void* d_out, int out_size, void* d_ws, size_t ws_size,
                              hipStream_t stream) {
    const float* x = (const float*)d_in[0];
    const void* ei = d_in[1];
    const float* W = (const float*)d_in[2];
    const float* b = (const float*)d_in[3];
    float* out = (float*)d_out;

    const int N = in_sizes[0] / 256;  // requires N < 2^24 and N <= 131072 (here 100000)
    const int E = in_sizes[1] / 2;
    const int NBUSE = (N + 255) >> BSH;       // 391 buckets used
    const int GEMMB = (N + 63) / 64;          // 1563 gemm blocks

    char* ws = (char*)d_ws;
    size_t o = 0;
    auto alloc = [&](size_t bytes) -> void* {
        void* p = ws + o;
        o += (bytes + 255) & ~(size_t)255;
        return p;
    };
    float* dinv = (float*)alloc((size_t)N * 4);
    unsigned short* g = (unsigned short*)alloc((size_t)N * 64 * 2);   // bf16 h, 12.8 MB
    unsigned* ebuf = (unsigned*)alloc((size_t)NBUSE * CAP * 4);       // bucketed edges, 12.8 MB
    int* cursor = (int*)alloc((size_t)NBUCK * 4);
    int* off = (int*)alloc((size_t)(N + 1) * 4);                      // final CSR offsets
    int* srcs = (int*)alloc((size_t)(E + N) * 4);                     // final CSR srcs (+self-loops)
    uint4* wpack = (uint4*)alloc((size_t)2048 * 16);                  // frag-layout bf16 W, 32 KB
    if (o > ws_size) return;  // fail visibly rather than corrupt

    k_packw<<<8, WG, 0, stream>>>(W, wpack, cursor);
    k_main<<<EBLK + GEMMB, WG, 0, stream>>>(ei, cursor, ebuf, E, x, wpack, g, N);
    k_csr<<<NBUSE, WG, 0, stream>>>(ebuf, cursor, off, srcs, dinv, N, NBUSE);
    k_gather<<<(N * 64 + WG - 1) / WG, WG, 0, stream>>>(g, off, srcs, dinv, b, out, N);
}